// Round 1
// 2679.139 us; speedup vs baseline: 1.0097x; 1.0097x over previous
//
#include <hip/hip_runtime.h>
#include <hip/hip_bf16.h>
#include <cmath>

#define NCH 117   // 9*13
#define NLEV 13

struct Consts {
  float lo[9];
  float inv[9];
  float w[11];
};

static Consts make_consts() {
  static const double rmin[9] = {170.0, 85000.0, -110.0, -80.0, 170.0, 0.0, -110.0, -100.0, -1000.0};
  static const double rmax[9] = {350.0, 110000.0, 110.0, 80.0, 350.0, 0.04, 110.0, 100.0, 60000.0};
  Consts c;
  for (int i = 0; i < 9; ++i) {
    float lo = (float)rmin[i];
    float hi = (float)rmax[i];
    c.lo[i] = lo;
    c.inv[i] = (float)(1.0 / (double)(hi - lo));
  }
  double g[11], s = 0.0;
  for (int k = 0; k < 11; ++k) {
    double d = (double)k - 5.0;
    g[k] = std::exp(-d * d / 4.5);
    s += g[k];
  }
  for (int k = 0; k < 11; ++k) c.w[k] = (float)(g[k] / s);
  return c;
}

// ---------------------------------------------------------------------------
// Kernel 1: fused pixel-loss partial sums + first 2x2 avg-pool (scale0->1).
// ---------------------------------------------------------------------------
__global__ __launch_bounds__(256)
void k_pool0(const float* __restrict__ x, const float* __restrict__ y,
             __hip_bfloat16* __restrict__ px, __hip_bfloat16* __restrict__ py,
             float2* __restrict__ part, Consts cst)
{
  const int H = 721, W = 1440, Hp = 361, Wp = 720;
  int idx = blockIdx.x * 256 + threadIdx.x;
  const int total = NCH * Hp * Wp;
  float s1 = 0.f, s2 = 0.f;
  if (idx < total) {
    int nc  = idx / (Hp * Wp);
    int rem = idx - nc * (Hp * Wp);
    int i = rem / Wp;
    int j = rem - i * Wp;
    int n = nc / NLEV;
    float lo = cst.lo[n], inv = cst.inv[n];
    const size_t cb = (size_t)nc * ((size_t)H * W);
    float sx = 0.f, sy = 0.f;
    #pragma unroll
    for (int dr = -1; dr <= 0; ++dr) {
      int r = 2 * i + dr;
      if (r < 0) continue;
      const float2* x2 = reinterpret_cast<const float2*>(x + cb + (size_t)r * W);
      const float2* y2 = reinterpret_cast<const float2*>(y + cb + (size_t)r * W);
      float2 xv = x2[j], yv = y2[j];
      float xr0 = fminf(fmaxf((xv.x - lo) * inv, 0.f), 1.f);
      float xr1 = fminf(fmaxf((xv.y - lo) * inv, 0.f), 1.f);
      float yr0 = fminf(fmaxf((yv.x - lo) * inv, 0.f), 1.f);
      float yr1 = fminf(fmaxf((yv.y - lo) * inv, 0.f), 1.f);
      float w0 = __expf(5.f * yr0 * yr0 * yr0) + 1.f;
      float w1 = __expf(5.f * yr1 * yr1 * yr1) + 1.f;
      float d0 = xr0 - yr0, d1 = xr1 - yr1;
      s1 += w0 * fabsf(d0) + w1 * fabsf(d1);
      s2 += (1.f - w0) * d0 * d0 + (1.f - w1) * d1 * d1;
      sx += xr0 + xr1;
      sy += yr0 + yr1;
    }
    px[idx] = __float2bfloat16(sx * 0.25f);
    py[idx] = __float2bfloat16(sy * 0.25f);
  }
  #pragma unroll
  for (int o = 32; o > 0; o >>= 1) { s1 += __shfl_down(s1, o); s2 += __shfl_down(s2, o); }
  __shared__ float ra[4], rb[4];
  int lane = threadIdx.x & 63, wid = threadIdx.x >> 6;
  if (lane == 0) { ra[wid] = s1; rb[wid] = s2; }
  __syncthreads();
  if (threadIdx.x == 0) {
    part[blockIdx.x] = make_float2(ra[0] + ra[1] + ra[2] + ra[3],
                                   rb[0] + rb[1] + rb[2] + rb[3]);
  }
}

// ---------------------------------------------------------------------------
// Generic 2x2 avg-pool for deeper scales.
// ---------------------------------------------------------------------------
template <typename Tin>
__global__ __launch_bounds__(256)
void k_pool(const Tin* __restrict__ x, const Tin* __restrict__ y,
            float* __restrict__ px, float* __restrict__ py,
            int H, int W, int Hp, int Wp)
{
  int idx = blockIdx.x * 256 + threadIdx.x;
  int total = NCH * Hp * Wp;
  if (idx >= total) return;
  int nc  = idx / (Hp * Wp);
  int rem = idx - nc * (Hp * Wp);
  int i = rem / Wp;
  int j = rem - i * Wp;
  const Tin* xc = x + (size_t)nc * ((size_t)H * W);
  const Tin* yc = y + (size_t)nc * ((size_t)H * W);
  float sx = 0.f, sy = 0.f;
  #pragma unroll
  for (int dr = -1; dr <= 0; ++dr) {
    int r = 2 * i + dr;
    if (r < 0) continue;
    size_t o = (size_t)r * W + 2 * j;
    sx += (float)xc[o] + (float)xc[o + 1];
    sy += (float)yc[o] + (float)yc[o + 1];
  }
  px[idx] = sx * 0.25f;
  py[idx] = sy * 0.25f;
}

// ---------------------------------------------------------------------------
// SSIM row-walking column-strip kernel.
// Block = 256 threads = 256 input columns = 246 output columns (halo fits
// exactly: 246 + 10 = 256). Walk RS+10 input rows. Per row:
//   - stage float2(x,y) row into 2-row ping-pong LDS (1 b64 write)
//   - horizontal 11-tap from LDS (11 b64 reads, products on the fly)
//   - vertical via 11-slot statically-indexed scatter accumulator:
//     row loop unrolled by 11 so slot/tap indices are compile-time (55 fma,
//     no register shifting, no div/mod).
// Output row (it-10) finalizes at iteration it; its slot is then zeroed and
// immediately reused for row (it+1).
//
// __launch_bounds__(256, 2): the 55-slot scatter accumulator MUST live in
// VGPRs. With the default occupancy-driven cap the backend allocated 84
// VGPRs and spilled the accumulator to scratch (rocprof: WRITE_SIZE=194MB
// per dispatch vs ~45KB of legitimate writes). Cap at 2 waves/EU -> 256
// VGPR budget -> no spill.
// ---------------------------------------------------------------------------
template <typename Tin, bool NORM, int RS = 100>
__global__ __launch_bounds__(256, 2)
void k_ssim(const Tin* __restrict__ X, const Tin* __restrict__ Y,
            int H, int W, int Ho, int Wo,
            float2* __restrict__ part, Consts cst)
{
  const float C1 = 1e-4f, C2 = 9e-4f;
  __shared__ float2 sxy[2][256];

  const int tid = threadIdx.x;
  const int nc = blockIdx.z;
  const int c0 = blockIdx.x * 246;
  const int r0 = blockIdx.y * RS;
  const int n_out = min(RS, Ho - r0);
  const int iters = n_out + 10;
  const int ci = c0 + tid;
  const bool in_col = ci < W;
  const bool do_out = (tid < 246) && (ci < Wo);

  const int n = nc / NLEV;
  const float lo = NORM ? cst.lo[n] : 0.f;
  const float inv = NORM ? cst.inv[n] : 1.f;
  const Tin* Xc = X + (size_t)nc * ((size_t)H * W);
  const Tin* Yc = Y + (size_t)nc * ((size_t)H * W);
  size_t off = (size_t)r0 * W + (size_t)(in_col ? ci : 0);

  float acc0[11], acc1[11], acc2[11], acc3[11], acc4[11];
  #pragma unroll
  for (int s = 0; s < 11; ++s) { acc0[s] = 0.f; acc1[s] = 0.f; acc2[s] = 0.f; acc3[s] = 0.f; acc4[s] = 0.f; }
  float csv = 0.f, ssv = 0.f;

  for (int itb = 0; itb < iters; itb += 11) {
    #pragma unroll
    for (int u = 0; u < 11; ++u) {
      const int it = itb + u;
      if (it < iters) {                       // block-uniform predicate
        float xv = 0.f, yv = 0.f;
        if (in_col) {
          xv = (float)Xc[off];
          yv = (float)Yc[off];
          if (NORM) {
            xv = fminf(fmaxf((xv - lo) * inv, 0.f), 1.f);
            yv = fminf(fmaxf((yv - lo) * inv, 0.f), 1.f);
          }
        }
        off += W;
        const int buf = it & 1;
        sxy[buf][tid] = make_float2(xv, yv);
        __syncthreads();
        if (do_out) {
          float hx = 0.f, hy = 0.f, hxx = 0.f, hyy = 0.f, hxy = 0.f;
          #pragma unroll
          for (int k = 0; k < 11; ++k) {
            float2 v = sxy[buf][tid + k];
            float w = cst.w[k];
            float wx = w * v.x, wy = w * v.y;
            hx  = fmaf(w, v.x, hx);
            hy  = fmaf(w, v.y, hy);
            hxx = fmaf(wx, v.x, hxx);
            hyy = fmaf(wy, v.y, hyy);
            hxy = fmaf(wx, v.y, hxy);
          }
          #pragma unroll
          for (int s = 0; s < 11; ++s) {
            const float wk = cst.w[(u - s + 11) % 11];   // compile-time index
            acc0[s] = fmaf(wk, hx,  acc0[s]);
            acc1[s] = fmaf(wk, hy,  acc1[s]);
            acc2[s] = fmaf(wk, hxx, acc2[s]);
            acc3[s] = fmaf(wk, hyy, acc3[s]);
            acc4[s] = fmaf(wk, hxy, acc4[s]);
          }
          const int sd = (u + 1) % 11;                   // compile-time
          if (it >= 10 && (it - 10) < n_out) {
            float mu1 = acc0[sd], mu2 = acc1[sd];
            float exx = acc2[sd], eyy = acc3[sd], exy = acc4[sd];
            float mu1s = mu1 * mu1, mu2s = mu2 * mu2, m12 = mu1 * mu2;
            float sg1 = exx - mu1s, sg2 = eyy - mu2s, sg12 = exy - m12;
            float cs = (2.f * sg12 + C2) / (sg1 + sg2 + C2);
            float ss = (2.f * m12 + C1) / (mu1s + mu2s + C1) * cs;
            csv += cs;
            ssv += ss;
          }
          acc0[sd] = 0.f; acc1[sd] = 0.f; acc2[sd] = 0.f; acc3[sd] = 0.f; acc4[sd] = 0.f;
        }
      }
    }
  }

  #pragma unroll
  for (int o = 32; o > 0; o >>= 1) { csv += __shfl_down(csv, o); ssv += __shfl_down(ssv, o); }
  __shared__ float ra[4], rb[4];
  int lane = tid & 63, wid = tid >> 6;
  if (lane == 0) { ra[wid] = csv; rb[wid] = ssv; }
  __syncthreads();
  if (tid == 0) {
    int tilesPerCh = gridDim.x * gridDim.y;
    int t = blockIdx.y * gridDim.x + blockIdx.x;
    part[(size_t)nc * tilesPerCh + t] =
        make_float2(ra[0] + ra[1] + ra[2] + ra[3], rb[0] + rb[1] + rb[2] + rb[3]);
  }
}

// ---------------------------------------------------------------------------
// Reductions (deterministic, fp64).
// ---------------------------------------------------------------------------
__global__ __launch_bounds__(256)
void k_reduce_pix(const float2* __restrict__ part, int n, double* __restrict__ acc)
{
  double a = 0.0, b = 0.0;
  for (int i = threadIdx.x; i < n; i += 256) { float2 v = part[i]; a += v.x; b += v.y; }
  __shared__ double sa[256], sb[256];
  sa[threadIdx.x] = a; sb[threadIdx.x] = b;
  __syncthreads();
  for (int o = 128; o > 0; o >>= 1) {
    if (threadIdx.x < o) { sa[threadIdx.x] += sa[threadIdx.x + o]; sb[threadIdx.x] += sb[threadIdx.x + o]; }
    __syncthreads();
  }
  if (threadIdx.x == 0) { acc[0] = sa[0]; acc[1] = sb[0]; }
}

__global__ __launch_bounds__(256)
void k_reduce_ssim(const float2* __restrict__ part, int tiles,
                   double* __restrict__ cs_out, double* __restrict__ ss_out)
{
  int nc = blockIdx.x;
  const float2* p = part + (size_t)nc * tiles;
  double a = 0.0, b = 0.0;
  for (int i = threadIdx.x; i < tiles; i += 256) { float2 v = p[i]; a += v.x; b += v.y; }
  __shared__ double sa[256], sb[256];
  sa[threadIdx.x] = a; sb[threadIdx.x] = b;
  __syncthreads();
  for (int o = 128; o > 0; o >>= 1) {
    if (threadIdx.x < o) { sa[threadIdx.x] += sa[threadIdx.x + o]; sb[threadIdx.x] += sb[threadIdx.x + o]; }
    __syncthreads();
  }
  if (threadIdx.x == 0) { cs_out[nc] = sa[0]; ss_out[nc] = sb[0]; }
}

// ---------------------------------------------------------------------------
// Finalize.
// ---------------------------------------------------------------------------
__global__ __launch_bounds__(128)
void k_final(const double* __restrict__ acc, float* __restrict__ out)
{
  const double msw[5]  = {0.0448, 0.2856, 0.3001, 0.2363, 0.1333};
  const double npix[5] = {711.0 * 1430.0, 351.0 * 710.0, 171.0 * 350.0,
                          81.0 * 170.0, 36.0 * 80.0};
  __shared__ double sh[128];
  double local = 0.0;
  for (int nc = threadIdx.x; nc < NCH; nc += 128) {
    double ms = 1.0;
    #pragma unroll
    for (int s = 0; s < 5; ++s) {
      double v = (s < 4) ? acc[2 + s * NCH + nc] : acc[2 + 5 * NCH + 4 * NCH + nc];
      v /= npix[s];
      if (v < 0.0) v = 0.0;
      ms *= pow(v, msw[s]);
    }
    local += ms;
  }
  sh[threadIdx.x] = local;
  __syncthreads();
  for (int o = 64; o > 0; o >>= 1) {
    if (threadIdx.x < o) sh[threadIdx.x] += sh[threadIdx.x + o];
    __syncthreads();
  }
  if (threadIdx.x == 0) {
    double ssim_loss = 1.0 - sh[0] / 117.0;
    const double Ntot = 9.0 * 13.0 * 721.0 * 1440.0;
    double pixel = 0.5 * (acc[0] + acc[1]) / Ntot;
    out[0] = (float)(ssim_loss + pixel);
  }
}

// ---------------------------------------------------------------------------
extern "C" void kernel_launch(void* const* d_in, const int* in_sizes, int n_in,
                              void* d_out, int out_size, void* d_ws, size_t ws_size,
                              hipStream_t stream)
{
  const float* x = (const float*)d_in[0];
  const float* y = (const float*)d_in[1];
  float* out = (float*)d_out;
  char* base = (char*)d_ws;
  const Consts cst = make_consts();
  const int RS = 100;

  const int HS[5] = {721, 361, 181, 91, 46};
  const int WS[5] = {1440, 720, 360, 180, 90};
  int tx[5], ty[5];
  for (int s = 0; s < 5; ++s) {
    int Ho = HS[s] - 10, Wo = WS[s] - 10;
    tx[s] = (Wo + 245) / 246;
    ty[s] = (Ho + RS - 1) / RS;
  }

  double* acc = (double*)base;
  size_t off = 16384;
  const int NB0 = (NCH * 361 * 720 + 255) / 256;
  float2* pix_part = (float2*)(base + off); off += (size_t)NB0 * sizeof(float2);
  off = (off + 255) & ~(size_t)255;
  float2* ss_part[5];
  for (int s = 0; s < 5; ++s) {
    ss_part[s] = (float2*)(base + off);
    off += (size_t)NCH * tx[s] * ty[s] * sizeof(float2);
    off = (off + 255) & ~(size_t)255;
  }
  size_t n1 = (size_t)NCH * 361 * 720;
  size_t n2 = (size_t)NCH * 181 * 360;
  size_t n3 = (size_t)NCH * 91 * 180;
  size_t n4 = (size_t)NCH * 46 * 90;
  __hip_bfloat16* bx1 = (__hip_bfloat16*)(base + off); off += n1 * 2;
  __hip_bfloat16* by1 = (__hip_bfloat16*)(base + off); off += n1 * 2;
  off = (off + 255) & ~(size_t)255;
  float* fx2 = (float*)(base + off); off += n2 * 4;
  float* fy2 = (float*)(base + off); off += n2 * 4;
  float* fx3 = (float*)(base + off); off += n3 * 4;
  float* fy3 = (float*)(base + off); off += n3 * 4;
  float* fx4 = (float*)(base + off); off += n4 * 4;
  float* fy4 = (float*)(base + off); off += n4 * 4;
  (void)ws_size; (void)in_sizes; (void)n_in; (void)out_size;

  k_pool0<<<NB0, 256, 0, stream>>>(x, y, bx1, by1, pix_part, cst);
  k_reduce_pix<<<1, 256, 0, stream>>>(pix_part, NB0, acc);

  {
    dim3 g(tx[0], ty[0], NCH);
    k_ssim<float, true><<<g, 256, 0, stream>>>(x, y, 721, 1440, 711, 1430, ss_part[0], cst);
  }
  {
    dim3 g(tx[1], ty[1], NCH);
    k_ssim<__hip_bfloat16, false><<<g, 256, 0, stream>>>(bx1, by1, 361, 720, 351, 710, ss_part[1], cst);
  }
  {
    int total = NCH * 181 * 360;
    k_pool<__hip_bfloat16><<<(total + 255) / 256, 256, 0, stream>>>(bx1, by1, fx2, fy2, 361, 720, 181, 360);
  }
  {
    dim3 g(tx[2], ty[2], NCH);
    k_ssim<float, false><<<g, 256, 0, stream>>>(fx2, fy2, 181, 360, 171, 350, ss_part[2], cst);
  }
  {
    int total = NCH * 91 * 180;
    k_pool<float><<<(total + 255) / 256, 256, 0, stream>>>(fx2, fy2, fx3, fy3, 181, 360, 91, 180);
  }
  {
    dim3 g(tx[3], ty[3], NCH);
    k_ssim<float, false><<<g, 256, 0, stream>>>(fx3, fy3, 91, 180, 81, 170, ss_part[3], cst);
  }
  {
    int total = NCH * 46 * 90;
    k_pool<float><<<(total + 255) / 256, 256, 0, stream>>>(fx3, fy3, fx4, fy4, 91, 180, 46, 90);
  }
  {
    dim3 g(tx[4], ty[4], NCH);
    k_ssim<float, false><<<g, 256, 0, stream>>>(fx4, fy4, 46, 90, 36, 80, ss_part[4], cst);
  }

  for (int s = 0; s < 5; ++s) {
    k_reduce_ssim<<<NCH, 256, 0, stream>>>(ss_part[s], tx[s] * ty[s],
                                           acc + 2 + s * NCH,
                                           acc + 2 + 5 * NCH + s * NCH);
  }

  k_final<<<1, 128, 0, stream>>>(acc, out);
}

// Round 2
// 1932.933 us; speedup vs baseline: 1.3995x; 1.3860x over previous
//
#include <hip/hip_runtime.h>
#include <hip/hip_bf16.h>
#include <cmath>

#define NCH 117   // 9*13
#define NLEV 13

typedef float v2f __attribute__((ext_vector_type(2)));

struct Consts {
  float lo[9];
  float inv[9];
  float w[11];
};

static Consts make_consts() {
  static const double rmin[9] = {170.0, 85000.0, -110.0, -80.0, 170.0, 0.0, -110.0, -100.0, -1000.0};
  static const double rmax[9] = {350.0, 110000.0, 110.0, 80.0, 350.0, 0.04, 110.0, 100.0, 60000.0};
  Consts c;
  for (int i = 0; i < 9; ++i) {
    float lo = (float)rmin[i];
    float hi = (float)rmax[i];
    c.lo[i] = lo;
    c.inv[i] = (float)(1.0 / (double)(hi - lo));
  }
  double g[11], s = 0.0;
  for (int k = 0; k < 11; ++k) {
    double d = (double)k - 5.0;
    g[k] = std::exp(-d * d / 4.5);
    s += g[k];
  }
  for (int k = 0; k < 11; ++k) c.w[k] = (float)(g[k] / s);
  return c;
}

__device__ __forceinline__ v2f v2clamp01(v2f v) {
  v2f z = {0.f, 0.f};
  v2f o = {1.f, 1.f};
#if __has_builtin(__builtin_elementwise_max) && __has_builtin(__builtin_elementwise_min)
  return __builtin_elementwise_min(__builtin_elementwise_max(v, z), o);
#else
  v.x = fminf(fmaxf(v.x, 0.f), 1.f);
  v.y = fminf(fmaxf(v.y, 0.f), 1.f);
  return v;
#endif
}

__device__ __forceinline__ float fast_rcp(float x) {
#if __has_builtin(__builtin_amdgcn_rcpf)
  return __builtin_amdgcn_rcpf(x);
#else
  return 1.f / x;
#endif
}

// ---------------------------------------------------------------------------
// Kernel 1: fused pixel-loss partial sums + first 2x2 avg-pool (scale0->1).
// ---------------------------------------------------------------------------
__global__ __launch_bounds__(256)
void k_pool0(const float* __restrict__ x, const float* __restrict__ y,
             __hip_bfloat16* __restrict__ px, __hip_bfloat16* __restrict__ py,
             float2* __restrict__ part, Consts cst)
{
  const int H = 721, W = 1440, Hp = 361, Wp = 720;
  int idx = blockIdx.x * 256 + threadIdx.x;
  const int total = NCH * Hp * Wp;
  float s1 = 0.f, s2 = 0.f;
  if (idx < total) {
    int nc  = idx / (Hp * Wp);
    int rem = idx - nc * (Hp * Wp);
    int i = rem / Wp;
    int j = rem - i * Wp;
    int n = nc / NLEV;
    float lo = cst.lo[n], inv = cst.inv[n];
    const size_t cb = (size_t)nc * ((size_t)H * W);
    float sx = 0.f, sy = 0.f;
    #pragma unroll
    for (int dr = -1; dr <= 0; ++dr) {
      int r = 2 * i + dr;
      if (r < 0) continue;
      const float2* x2 = reinterpret_cast<const float2*>(x + cb + (size_t)r * W);
      const float2* y2 = reinterpret_cast<const float2*>(y + cb + (size_t)r * W);
      float2 xv = x2[j], yv = y2[j];
      float xr0 = fminf(fmaxf((xv.x - lo) * inv, 0.f), 1.f);
      float xr1 = fminf(fmaxf((xv.y - lo) * inv, 0.f), 1.f);
      float yr0 = fminf(fmaxf((yv.x - lo) * inv, 0.f), 1.f);
      float yr1 = fminf(fmaxf((yv.y - lo) * inv, 0.f), 1.f);
      float w0 = __expf(5.f * yr0 * yr0 * yr0) + 1.f;
      float w1 = __expf(5.f * yr1 * yr1 * yr1) + 1.f;
      float d0 = xr0 - yr0, d1 = xr1 - yr1;
      s1 += w0 * fabsf(d0) + w1 * fabsf(d1);
      s2 += (1.f - w0) * d0 * d0 + (1.f - w1) * d1 * d1;
      sx += xr0 + xr1;
      sy += yr0 + yr1;
    }
    px[idx] = __float2bfloat16(sx * 0.25f);
    py[idx] = __float2bfloat16(sy * 0.25f);
  }
  #pragma unroll
  for (int o = 32; o > 0; o >>= 1) { s1 += __shfl_down(s1, o); s2 += __shfl_down(s2, o); }
  __shared__ float ra[4], rb[4];
  int lane = threadIdx.x & 63, wid = threadIdx.x >> 6;
  if (lane == 0) { ra[wid] = s1; rb[wid] = s2; }
  __syncthreads();
  if (threadIdx.x == 0) {
    part[blockIdx.x] = make_float2(ra[0] + ra[1] + ra[2] + ra[3],
                                   rb[0] + rb[1] + rb[2] + rb[3]);
  }
}

// ---------------------------------------------------------------------------
// Generic 2x2 avg-pool for deeper scales.
// ---------------------------------------------------------------------------
template <typename Tin>
__global__ __launch_bounds__(256)
void k_pool(const Tin* __restrict__ x, const Tin* __restrict__ y,
            float* __restrict__ px, float* __restrict__ py,
            int H, int W, int Hp, int Wp)
{
  int idx = blockIdx.x * 256 + threadIdx.x;
  int total = NCH * Hp * Wp;
  if (idx >= total) return;
  int nc  = idx / (Hp * Wp);
  int rem = idx - nc * (Hp * Wp);
  int i = rem / Wp;
  int j = rem - i * Wp;
  const Tin* xc = x + (size_t)nc * ((size_t)H * W);
  const Tin* yc = y + (size_t)nc * ((size_t)H * W);
  float sx = 0.f, sy = 0.f;
  #pragma unroll
  for (int dr = -1; dr <= 0; ++dr) {
    int r = 2 * i + dr;
    if (r < 0) continue;
    size_t o = (size_t)r * W + 2 * j;
    sx += (float)xc[o] + (float)xc[o + 1];
    sy += (float)yc[o] + (float)yc[o + 1];
  }
  px[idx] = sx * 0.25f;
  py[idx] = sy * 0.25f;
}

// ---------------------------------------------------------------------------
// SSIM row-walking column-strip kernel — packed-f32 (VOP3P) version.
//
// Moments are packed: m1=(hx,hy), m2=(hxx,hyy) as v2f so the backend can
// emit v_pk_{mul,add,fma}_f32 (2 f32 lanes per issue); mxy stays scalar.
//   horizontal per tap: pk_mul + pk_add + pk_fma + fma   (4 vs 7 scalar)
//   vertical per slot : 2x pk_fma + fma                  (3 vs 5 scalar)
// Finalize divides use v_rcp_f32. Slot zeroing is folded into the first
// accumulation of a fresh slot (weight w[0] tap becomes an assignment).
// Next row's x/y are prefetched before the barrier to hide global latency.
//
// Rocprof evidence for this direction: scale-0 dispatch shows HBM 538 GB/s
// (8.5% of achievable), 0 bank conflicts, MfmaUtil 0, VALUBusy 77% ->
// VALU-issue-bound. (Round-0 spill theory was falsified: launch_bounds(256,2)
// changed neither VGPR=84 nor WRITE_SIZE; 195MB WRITE is L2 victim traffic.)
// ---------------------------------------------------------------------------
template <typename Tin, bool NORM, int RS = 100>
__global__ __launch_bounds__(256)
void k_ssim(const Tin* __restrict__ X, const Tin* __restrict__ Y,
            int H, int W, int Ho, int Wo,
            float2* __restrict__ part, Consts cst)
{
  const float C1 = 1e-4f, C2 = 9e-4f;
  __shared__ v2f sxy[2][256];

  const int tid = threadIdx.x;
  const int nc = blockIdx.z;
  const int c0 = blockIdx.x * 246;
  const int r0 = blockIdx.y * RS;
  const int n_out = min(RS, Ho - r0);
  const int iters = n_out + 10;
  const int ci = c0 + tid;
  const bool in_col = ci < W;
  const bool do_out = (tid < 246) && (ci < Wo);

  const int n = nc / NLEV;
  const float lo = NORM ? cst.lo[n] : 0.f;
  const float inv = NORM ? cst.inv[n] : 1.f;
  const Tin* Xc = X + (size_t)nc * ((size_t)H * W);
  const Tin* Yc = Y + (size_t)nc * ((size_t)H * W);

  // 32-bit byte offsets (max channel size 721*1440*4B = 4.15MB < 2^31) so
  // loads use the SGPR-base + 32-bit voffset form.
  const unsigned Wb = (unsigned)W * (unsigned)sizeof(Tin);
  unsigned offb = (unsigned)(r0 * W + (in_col ? ci : 0)) * (unsigned)sizeof(Tin);

  v2f accM[11];    // (mu1, mu2) vertical accumulators
  v2f accS[11];    // (E[x^2], E[y^2])
  float accXY[11]; // E[xy]
  #pragma unroll
  for (int s = 0; s < 11; ++s) {
    accM[s] = (v2f){0.f, 0.f};
    accS[s] = (v2f){0.f, 0.f};
    accXY[s] = 0.f;
  }
  float csv = 0.f, ssv = 0.f;

  // prologue: load row 0
  float xv = 0.f, yv = 0.f;
  if (in_col) {
    xv = (float)*(const Tin*)((const char*)Xc + offb);
    yv = (float)*(const Tin*)((const char*)Yc + offb);
  }
  offb += Wb;

  for (int itb = 0; itb < iters; itb += 11) {
    #pragma unroll
    for (int u = 0; u < 11; ++u) {
      const int it = itb + u;
      if (it < iters) {                       // block-uniform predicate
        // stage current row (normalized) into ping-pong LDS
        const int buf = it & 1;
        v2f p = {xv, yv};
        if (NORM) p = v2clamp01((p - lo) * inv);
        sxy[buf][tid] = p;
        // prefetch next row before the barrier (hides global latency)
        xv = 0.f; yv = 0.f;
        if (in_col && (it + 1 < iters)) {
          xv = (float)*(const Tin*)((const char*)Xc + offb);
          yv = (float)*(const Tin*)((const char*)Yc + offb);
        }
        offb += Wb;
        __syncthreads();
        if (do_out) {
          // horizontal 11-tap: packed moments
          v2f m1 = {0.f, 0.f};
          v2f m2 = {0.f, 0.f};
          float mxy = 0.f;
          const v2f* row = &sxy[buf][tid];
          #pragma unroll
          for (int k = 0; k < 11; ++k) {
            v2f v = row[k];
            float w = cst.w[k];
            v2f wv = w * v;                 // pk_mul
            m1 += wv;                        // pk_add
            m2 += wv * v;                    // pk_fma
            mxy = fmaf(wv.x, v.y, mxy);      // fma
          }
          // vertical scatter: slot s==u is fresh (was finalized at the
          // previous row) -> assignment with w[0]; others accumulate.
          #pragma unroll
          for (int s = 0; s < 11; ++s) {
            const float wk = cst.w[(u - s + 11) % 11];   // compile-time index
            if (s == u) {
              accM[s] = wk * m1;                         // pk_mul
              accS[s] = wk * m2;                         // pk_mul
              accXY[s] = wk * mxy;                       // mul
            } else {
              accM[s] += wk * m1;                        // pk_fma
              accS[s] += wk * m2;                        // pk_fma
              accXY[s] = fmaf(wk, mxy, accXY[s]);        // fma
            }
          }
          if (it >= 10) {
            const int sd = (u + 1) % 11;                 // compile-time
            v2f mu = accM[sd];
            v2f e  = accS[sd];
            float exy = accXY[sd];
            float mu1s = mu.x * mu.x, mu2s = mu.y * mu.y, m12 = mu.x * mu.y;
            float sg12 = exy - m12;
            float den_cs = (e.x - mu1s) + (e.y - mu2s) + C2;
            float cs = (2.f * sg12 + C2) * fast_rcp(den_cs);
            float ss = (2.f * m12 + C1) * fast_rcp(mu1s + mu2s + C1) * cs;
            csv += cs;
            ssv += ss;
          }
        }
      }
    }
  }

  #pragma unroll
  for (int o = 32; o > 0; o >>= 1) { csv += __shfl_down(csv, o); ssv += __shfl_down(ssv, o); }
  __shared__ float ra[4], rb[4];
  int lane = tid & 63, wid = tid >> 6;
  if (lane == 0) { ra[wid] = csv; rb[wid] = ssv; }
  __syncthreads();
  if (tid == 0) {
    int tilesPerCh = gridDim.x * gridDim.y;
    int t = blockIdx.y * gridDim.x + blockIdx.x;
    part[(size_t)nc * tilesPerCh + t] =
        make_float2(ra[0] + ra[1] + ra[2] + ra[3], rb[0] + rb[1] + rb[2] + rb[3]);
  }
}

// ---------------------------------------------------------------------------
// Reductions (deterministic, fp64).
// ---------------------------------------------------------------------------
__global__ __launch_bounds__(256)
void k_reduce_pix(const float2* __restrict__ part, int n, double* __restrict__ acc)
{
  double a = 0.0, b = 0.0;
  for (int i = threadIdx.x; i < n; i += 256) { float2 v = part[i]; a += v.x; b += v.y; }
  __shared__ double sa[256], sb[256];
  sa[threadIdx.x] = a; sb[threadIdx.x] = b;
  __syncthreads();
  for (int o = 128; o > 0; o >>= 1) {
    if (threadIdx.x < o) { sa[threadIdx.x] += sa[threadIdx.x + o]; sb[threadIdx.x] += sb[threadIdx.x + o]; }
    __syncthreads();
  }
  if (threadIdx.x == 0) { acc[0] = sa[0]; acc[1] = sb[0]; }
}

__global__ __launch_bounds__(256)
void k_reduce_ssim(const float2* __restrict__ part, int tiles,
                   double* __restrict__ cs_out, double* __restrict__ ss_out)
{
  int nc = blockIdx.x;
  const float2* p = part + (size_t)nc * tiles;
  double a = 0.0, b = 0.0;
  for (int i = threadIdx.x; i < tiles; i += 256) { float2 v = p[i]; a += v.x; b += v.y; }
  __shared__ double sa[256], sb[256];
  sa[threadIdx.x] = a; sb[threadIdx.x] = b;
  __syncthreads();
  for (int o = 128; o > 0; o >>= 1) {
    if (threadIdx.x < o) { sa[threadIdx.x] += sa[threadIdx.x + o]; sb[threadIdx.x] += sb[threadIdx.x + o]; }
    __syncthreads();
  }
  if (threadIdx.x == 0) { cs_out[nc] = sa[0]; ss_out[nc] = sb[0]; }
}

// ---------------------------------------------------------------------------
// Finalize.
// ---------------------------------------------------------------------------
__global__ __launch_bounds__(128)
void k_final(const double* __restrict__ acc, float* __restrict__ out)
{
  const double msw[5]  = {0.0448, 0.2856, 0.3001, 0.2363, 0.1333};
  const double npix[5] = {711.0 * 1430.0, 351.0 * 710.0, 171.0 * 350.0,
                          81.0 * 170.0, 36.0 * 80.0};
  __shared__ double sh[128];
  double local = 0.0;
  for (int nc = threadIdx.x; nc < NCH; nc += 128) {
    double ms = 1.0;
    #pragma unroll
    for (int s = 0; s < 5; ++s) {
      double v = (s < 4) ? acc[2 + s * NCH + nc] : acc[2 + 5 * NCH + 4 * NCH + nc];
      v /= npix[s];
      if (v < 0.0) v = 0.0;
      ms *= pow(v, msw[s]);
    }
    local += ms;
  }
  sh[threadIdx.x] = local;
  __syncthreads();
  for (int o = 64; o > 0; o >>= 1) {
    if (threadIdx.x < o) sh[threadIdx.x] += sh[threadIdx.x + o];
    __syncthreads();
  }
  if (threadIdx.x == 0) {
    double ssim_loss = 1.0 - sh[0] / 117.0;
    const double Ntot = 9.0 * 13.0 * 721.0 * 1440.0;
    double pixel = 0.5 * (acc[0] + acc[1]) / Ntot;
    out[0] = (float)(ssim_loss + pixel);
  }
}

// ---------------------------------------------------------------------------
extern "C" void kernel_launch(void* const* d_in, const int* in_sizes, int n_in,
                              void* d_out, int out_size, void* d_ws, size_t ws_size,
                              hipStream_t stream)
{
  const float* x = (const float*)d_in[0];
  const float* y = (const float*)d_in[1];
  float* out = (float*)d_out;
  char* base = (char*)d_ws;
  const Consts cst = make_consts();
  const int RS = 100;

  const int HS[5] = {721, 361, 181, 91, 46};
  const int WS[5] = {1440, 720, 360, 180, 90};
  int tx[5], ty[5];
  for (int s = 0; s < 5; ++s) {
    int Ho = HS[s] - 10, Wo = WS[s] - 10;
    tx[s] = (Wo + 245) / 246;
    ty[s] = (Ho + RS - 1) / RS;
  }

  double* acc = (double*)base;
  size_t off = 16384;
  const int NB0 = (NCH * 361 * 720 + 255) / 256;
  float2* pix_part = (float2*)(base + off); off += (size_t)NB0 * sizeof(float2);
  off = (off + 255) & ~(size_t)255;
  float2* ss_part[5];
  for (int s = 0; s < 5; ++s) {
    ss_part[s] = (float2*)(base + off);
    off += (size_t)NCH * tx[s] * ty[s] * sizeof(float2);
    off = (off + 255) & ~(size_t)255;
  }
  size_t n1 = (size_t)NCH * 361 * 720;
  size_t n2 = (size_t)NCH * 181 * 360;
  size_t n3 = (size_t)NCH * 91 * 180;
  size_t n4 = (size_t)NCH * 46 * 90;
  __hip_bfloat16* bx1 = (__hip_bfloat16*)(base + off); off += n1 * 2;
  __hip_bfloat16* by1 = (__hip_bfloat16*)(base + off); off += n1 * 2;
  off = (off + 255) & ~(size_t)255;
  float* fx2 = (float*)(base + off); off += n2 * 4;
  float* fy2 = (float*)(base + off); off += n2 * 4;
  float* fx3 = (float*)(base + off); off += n3 * 4;
  float* fy3 = (float*)(base + off); off += n3 * 4;
  float* fx4 = (float*)(base + off); off += n4 * 4;
  float* fy4 = (float*)(base + off); off += n4 * 4;
  (void)ws_size; (void)in_sizes; (void)n_in; (void)out_size;

  k_pool0<<<NB0, 256, 0, stream>>>(x, y, bx1, by1, pix_part, cst);
  k_reduce_pix<<<1, 256, 0, stream>>>(pix_part, NB0, acc);

  {
    dim3 g(tx[0], ty[0], NCH);
    k_ssim<float, true><<<g, 256, 0, stream>>>(x, y, 721, 1440, 711, 1430, ss_part[0], cst);
  }
  {
    dim3 g(tx[1], ty[1], NCH);
    k_ssim<__hip_bfloat16, false><<<g, 256, 0, stream>>>(bx1, by1, 361, 720, 351, 710, ss_part[1], cst);
  }
  {
    int total = NCH * 181 * 360;
    k_pool<__hip_bfloat16><<<(total + 255) / 256, 256, 0, stream>>>(bx1, by1, fx2, fy2, 361, 720, 181, 360);
  }
  {
    dim3 g(tx[2], ty[2], NCH);
    k_ssim<float, false><<<g, 256, 0, stream>>>(fx2, fy2, 181, 360, 171, 350, ss_part[2], cst);
  }
  {
    int total = NCH * 91 * 180;
    k_pool<float><<<(total + 255) / 256, 256, 0, stream>>>(fx2, fy2, fx3, fy3, 181, 360, 91, 180);
  }
  {
    dim3 g(tx[3], ty[3], NCH);
    k_ssim<float, false><<<g, 256, 0, stream>>>(fx3, fy3, 91, 180, 81, 170, ss_part[3], cst);
  }
  {
    int total = NCH * 46 * 90;
    k_pool<float><<<(total + 255) / 256, 256, 0, stream>>>(fx3, fy3, fx4, fy4, 91, 180, 46, 90);
  }
  {
    dim3 g(tx[4], ty[4], NCH);
    k_ssim<float, false><<<g, 256, 0, stream>>>(fx4, fy4, 46, 90, 36, 80, ss_part[4], cst);
  }

  for (int s = 0; s < 5; ++s) {
    k_reduce_ssim<<<NCH, 256, 0, stream>>>(ss_part[s], tx[s] * ty[s],
                                           acc + 2 + s * NCH,
                                           acc + 2 + 5 * NCH + s * NCH);
  }

  k_final<<<1, 128, 0, stream>>>(acc, out);
}

// Round 3
// 1544.855 us; speedup vs baseline: 1.7510x; 1.2512x over previous
//
#include <hip/hip_runtime.h>
#include <hip/hip_bf16.h>
#include <cmath>

#define NCH 117   // 9*13
#define NLEV 13

typedef float v2f __attribute__((ext_vector_type(2)));

struct Consts {
  float lo[9];
  float inv[9];
  float w[11];
};

static Consts make_consts() {
  static const double rmin[9] = {170.0, 85000.0, -110.0, -80.0, 170.0, 0.0, -110.0, -100.0, -1000.0};
  static const double rmax[9] = {350.0, 110000.0, 110.0, 80.0, 350.0, 0.04, 110.0, 100.0, 60000.0};
  Consts c;
  for (int i = 0; i < 9; ++i) {
    float lo = (float)rmin[i];
    float hi = (float)rmax[i];
    c.lo[i] = lo;
    c.inv[i] = (float)(1.0 / (double)(hi - lo));
  }
  double g[11], s = 0.0;
  for (int k = 0; k < 11; ++k) {
    double d = (double)k - 5.0;
    g[k] = std::exp(-d * d / 4.5);
    s += g[k];
  }
  for (int k = 0; k < 11; ++k) c.w[k] = (float)(g[k] / s);
  return c;
}

__device__ __forceinline__ v2f v2clamp01(v2f v) {
  v2f z = {0.f, 0.f};
  v2f o = {1.f, 1.f};
#if __has_builtin(__builtin_elementwise_max) && __has_builtin(__builtin_elementwise_min)
  return __builtin_elementwise_min(__builtin_elementwise_max(v, z), o);
#else
  v.x = fminf(fmaxf(v.x, 0.f), 1.f);
  v.y = fminf(fmaxf(v.y, 0.f), 1.f);
  return v;
#endif
}

__device__ __forceinline__ float fast_rcp(float x) {
#if __has_builtin(__builtin_amdgcn_rcpf)
  return __builtin_amdgcn_rcpf(x);
#else
  return 1.f / x;
#endif
}

__device__ __forceinline__ void store_pool(__hip_bfloat16* p, float v) { *p = __float2bfloat16(v); }
__device__ __forceinline__ void store_pool(float* p, float v) { *p = v; }

// ---------------------------------------------------------------------------
// Fused SSIM + 2x2-avg-pool (+ pixel loss for scale 0) row-walking kernel.
//
// SSIM core unchanged from the packed-f32 (VOP3P) version: 2-row ping-pong
// LDS, horizontal 11-tap with packed moments, 11-slot statically-indexed
// vertical scatter accumulator, v_rcp_f32 finalize.
//
// New fusions (removes k_pool0 + 3x k_pool = a full extra pass over x,y):
//  - POOL: emits the 2x2 avg-pooled next-scale input. Row windows are
//    (2i-1, 2i) [reference pads H odd by (1,1)]; col windows (2j, 2j+1).
//    On odd rows a register pair-accumulator captures its column pair from
//    the CURRENT LDS buffer (no cross-buffer read -> no WAR hazard); on even
//    rows the window completes and is stored. Summation order replicates the
//    old k_pool0/k_pool exactly (bit-identical outputs).
//    Row ownership: even r in (r0, r0+RS]  (plus r==0 for the first tile);
//    col ownership: even tid < 246 -> j = 123*bx + tid/2 (disjoint, complete).
//  - PIX (scale 0 only): weighted pixel-loss partials from the normalized
//    register value. Row ownership [r0, r0+RS) (last tile extends to H);
//    col ownership tid < 246.
// ---------------------------------------------------------------------------
template <typename Tin, typename Tp, bool NORM, bool POOL, bool PIX, int RS>
__global__ __launch_bounds__(256)
void k_ssim(const Tin* __restrict__ X, const Tin* __restrict__ Y,
            Tp* __restrict__ PX, Tp* __restrict__ PY,
            int H, int W, int Ho, int Wo, int Hp, int Wp,
            float2* __restrict__ part, float2* __restrict__ pixpart, Consts cst)
{
  const float C1 = 1e-4f, C2 = 9e-4f;
  __shared__ v2f sxy[2][256];

  const int tid = threadIdx.x;
  const int nc = blockIdx.z;
  const int c0 = blockIdx.x * 246;
  const int r0 = blockIdx.y * RS;
  const int n_out = min(RS, Ho - r0);
  const int iters = n_out + 10;
  const int ci = c0 + tid;
  const bool in_col = ci < W;
  const bool do_out = (tid < 246) && (ci < Wo);

  const int n = nc / NLEV;
  const float lo = NORM ? cst.lo[n] : 0.f;
  const float inv = NORM ? cst.inv[n] : 1.f;
  const Tin* Xc = X + (size_t)nc * ((size_t)H * W);
  const Tin* Yc = Y + (size_t)nc * ((size_t)H * W);

  // pooling ownership
  const int jcol = (c0 + tid) >> 1;
  const bool pool_thr = POOL && ((tid & 1) == 0) && (tid < 246) && (jcol < Wp);
  const int r_hi = r0 + RS;
  const size_t poolBase = POOL ? (size_t)nc * ((size_t)Hp * Wp) : 0;
  float paccx = 0.f, paccy = 0.f;

  // pixel-loss ownership
  const int pix_end = PIX ? ((blockIdx.y == gridDim.y - 1) ? H : (r0 + RS)) : 0;
  const bool own_col = (tid < 246) && (ci < W);
  float s1 = 0.f, s2 = 0.f;

  // 32-bit byte offsets (max channel size 721*1440*4B = 4.15MB < 2^31)
  const unsigned Wb = (unsigned)W * (unsigned)sizeof(Tin);
  unsigned offb = (unsigned)(r0 * W + (in_col ? ci : 0)) * (unsigned)sizeof(Tin);

  v2f accM[11];    // (mu1, mu2)
  v2f accS[11];    // (E[x^2], E[y^2])
  float accXY[11]; // E[xy]
  #pragma unroll
  for (int s = 0; s < 11; ++s) {
    accM[s] = (v2f){0.f, 0.f};
    accS[s] = (v2f){0.f, 0.f};
    accXY[s] = 0.f;
  }
  float csv = 0.f, ssv = 0.f;

  // prologue: load row 0
  float xv = 0.f, yv = 0.f;
  if (in_col) {
    xv = (float)*(const Tin*)((const char*)Xc + offb);
    yv = (float)*(const Tin*)((const char*)Yc + offb);
  }
  offb += Wb;

  for (int itb = 0; itb < iters; itb += 11) {
    #pragma unroll
    for (int u = 0; u < 11; ++u) {
      const int it = itb + u;
      if (it < iters) {                       // block-uniform predicate
        const int r = r0 + it;
        const int buf = it & 1;
        v2f p = {xv, yv};
        if (NORM) p = v2clamp01((p - lo) * inv);
        if constexpr (PIX) {
          if (own_col && r < pix_end) {
            float d = p.x - p.y;
            float w = __expf(5.f * p.y * p.y * p.y) + 1.f;
            s1 += w * fabsf(d);
            s2 += (1.f - w) * d * d;
          }
        }
        sxy[buf][tid] = p;
        // prefetch next row before the barrier
        xv = 0.f; yv = 0.f;
        if (in_col && (it + 1 < iters)) {
          xv = (float)*(const Tin*)((const char*)Xc + offb);
          yv = (float)*(const Tin*)((const char*)Yc + offb);
        }
        offb += Wb;
        __syncthreads();
        if constexpr (POOL) {
          if (pool_thr) {
            v2f a = sxy[buf][tid];
            v2f b2 = sxy[buf][tid + 1];
            float qx = a.x + b2.x;
            float qy = a.y + b2.y;
            if ((r & 1) == 0) {
              if ((r > r0 && r <= r_hi) || r == 0) {
                float fx = ((r == 0) ? qx : (paccx + qx)) * 0.25f;
                float fy = ((r == 0) ? qy : (paccy + qy)) * 0.25f;
                size_t pidx = poolBase + (size_t)(r >> 1) * (size_t)Wp + (size_t)jcol;
                store_pool(PX + pidx, fx);
                store_pool(PY + pidx, fy);
              }
            } else {
              paccx = qx; paccy = qy;
            }
          }
        }
        if (do_out) {
          // horizontal 11-tap: packed moments
          v2f m1 = {0.f, 0.f};
          v2f m2 = {0.f, 0.f};
          float mxy = 0.f;
          const v2f* row = &sxy[buf][tid];
          #pragma unroll
          for (int k = 0; k < 11; ++k) {
            v2f v = row[k];
            float w = cst.w[k];
            v2f wv = w * v;                  // pk_mul
            m1 += wv;                         // pk_add
            m2 += wv * v;                     // pk_fma
            mxy = fmaf(wv.x, v.y, mxy);       // fma
          }
          // vertical scatter: slot s==u is fresh -> assignment with w[0]
          #pragma unroll
          for (int s = 0; s < 11; ++s) {
            const float wk = cst.w[(u - s + 11) % 11];   // compile-time index
            if (s == u) {
              accM[s] = wk * m1;
              accS[s] = wk * m2;
              accXY[s] = wk * mxy;
            } else {
              accM[s] += wk * m1;
              accS[s] += wk * m2;
              accXY[s] = fmaf(wk, mxy, accXY[s]);
            }
          }
          if (it >= 10) {
            const int sd = (u + 1) % 11;                 // compile-time
            v2f mu = accM[sd];
            v2f e  = accS[sd];
            float exy = accXY[sd];
            float mu1s = mu.x * mu.x, mu2s = mu.y * mu.y, m12 = mu.x * mu.y;
            float sg12 = exy - m12;
            float den_cs = (e.x - mu1s) + (e.y - mu2s) + C2;
            float cs = (2.f * sg12 + C2) * fast_rcp(den_cs);
            float ss = (2.f * m12 + C1) * fast_rcp(mu1s + mu2s + C1) * cs;
            csv += cs;
            ssv += ss;
          }
        }
      }
    }
  }

  #pragma unroll
  for (int o = 32; o > 0; o >>= 1) {
    csv += __shfl_down(csv, o); ssv += __shfl_down(ssv, o);
    if constexpr (PIX) { s1 += __shfl_down(s1, o); s2 += __shfl_down(s2, o); }
  }
  __shared__ float ra[4], rb[4], rc[4], rd[4];
  int lane = tid & 63, wid = tid >> 6;
  if (lane == 0) {
    ra[wid] = csv; rb[wid] = ssv;
    if constexpr (PIX) { rc[wid] = s1; rd[wid] = s2; }
  }
  __syncthreads();
  if (tid == 0) {
    int tilesPerCh = gridDim.x * gridDim.y;
    int t = blockIdx.y * gridDim.x + blockIdx.x;
    part[(size_t)nc * tilesPerCh + t] =
        make_float2(ra[0] + ra[1] + ra[2] + ra[3], rb[0] + rb[1] + rb[2] + rb[3]);
    if constexpr (PIX) {
      pixpart[(size_t)nc * tilesPerCh + t] =
          make_float2(rc[0] + rc[1] + rc[2] + rc[3], rd[0] + rd[1] + rd[2] + rd[3]);
    }
  }
}

// ---------------------------------------------------------------------------
// Merged per-channel SSIM reductions for all 5 scales (deterministic, fp64).
// grid = (NCH, 5)
// ---------------------------------------------------------------------------
struct RedArgs {
  const float2* p[5];
  int tiles[5];
};

__global__ __launch_bounds__(256)
void k_reduce_all(RedArgs ra, double* __restrict__ acc)
{
  int s = blockIdx.y;
  int nc = blockIdx.x;
  int tiles = ra.tiles[s];
  const float2* p = ra.p[s] + (size_t)nc * tiles;
  double a = 0.0, b = 0.0;
  for (int i = threadIdx.x; i < tiles; i += 256) { float2 v = p[i]; a += v.x; b += v.y; }
  __shared__ double sa[256], sb[256];
  sa[threadIdx.x] = a; sb[threadIdx.x] = b;
  __syncthreads();
  for (int o = 128; o > 0; o >>= 1) {
    if (threadIdx.x < o) { sa[threadIdx.x] += sa[threadIdx.x + o]; sb[threadIdx.x] += sb[threadIdx.x + o]; }
    __syncthreads();
  }
  if (threadIdx.x == 0) {
    acc[2 + s * NCH + nc] = sa[0];             // cs sum
    acc[2 + 5 * NCH + s * NCH + nc] = sb[0];   // ss sum
  }
}

// ---------------------------------------------------------------------------
// Finalize (also reduces the pixel-loss partials; deterministic fp64).
// ---------------------------------------------------------------------------
__global__ __launch_bounds__(256)
void k_final(const double* __restrict__ acc, const float2* __restrict__ pixpart,
             int npart, float* __restrict__ out)
{
  const double msw[5]  = {0.0448, 0.2856, 0.3001, 0.2363, 0.1333};
  const double npix[5] = {711.0 * 1430.0, 351.0 * 710.0, 171.0 * 350.0,
                          81.0 * 170.0, 36.0 * 80.0};
  int tid = threadIdx.x;
  __shared__ double sa[256], sb[256];
  double a = 0.0, b = 0.0;
  for (int i = tid; i < npart; i += 256) { float2 v = pixpart[i]; a += v.x; b += v.y; }
  sa[tid] = a; sb[tid] = b;
  __syncthreads();
  for (int o = 128; o > 0; o >>= 1) {
    if (tid < o) { sa[tid] += sa[tid + o]; sb[tid] += sb[tid + o]; }
    __syncthreads();
  }
  double pixA = sa[0], pixB = sb[0];
  __syncthreads();

  __shared__ double sh[256];
  double local = 0.0;
  for (int nc = tid; nc < NCH; nc += 256) {
    double ms = 1.0;
    #pragma unroll
    for (int s = 0; s < 5; ++s) {
      double v = (s < 4) ? acc[2 + s * NCH + nc] : acc[2 + 5 * NCH + 4 * NCH + nc];
      v /= npix[s];
      if (v < 0.0) v = 0.0;
      ms *= pow(v, msw[s]);
    }
    local += ms;
  }
  sh[tid] = local;
  __syncthreads();
  for (int o = 128; o > 0; o >>= 1) {
    if (tid < o) sh[tid] += sh[tid + o];
    __syncthreads();
  }
  if (tid == 0) {
    double ssim_loss = 1.0 - sh[0] / 117.0;
    const double Ntot = 9.0 * 13.0 * 721.0 * 1440.0;
    double pixel = 0.5 * (pixA + pixB) / Ntot;
    out[0] = (float)(ssim_loss + pixel);
  }
}

// ---------------------------------------------------------------------------
extern "C" void kernel_launch(void* const* d_in, const int* in_sizes, int n_in,
                              void* d_out, int out_size, void* d_ws, size_t ws_size,
                              hipStream_t stream)
{
  const float* x = (const float*)d_in[0];
  const float* y = (const float*)d_in[1];
  float* out = (float*)d_out;
  char* base = (char*)d_ws;
  const Consts cst = make_consts();
  const int RS = 120;

  const int HS[5] = {721, 361, 181, 91, 46};
  const int WS[5] = {1440, 720, 360, 180, 90};
  int tx[5], ty[5];
  for (int s = 0; s < 5; ++s) {
    int Ho = HS[s] - 10, Wo = WS[s] - 10;
    tx[s] = (Wo + 245) / 246;
    ty[s] = (Ho + RS - 1) / RS;
  }

  double* acc = (double*)base;
  size_t off = 16384;
  float2* ss_part[5];
  for (int s = 0; s < 5; ++s) {
    ss_part[s] = (float2*)(base + off);
    off += (size_t)NCH * tx[s] * ty[s] * sizeof(float2);
    off = (off + 255) & ~(size_t)255;
  }
  const int npix_part = NCH * tx[0] * ty[0];
  float2* pix_part = (float2*)(base + off); off += (size_t)npix_part * sizeof(float2);
  off = (off + 255) & ~(size_t)255;

  size_t n1 = (size_t)NCH * 361 * 720;
  size_t n2 = (size_t)NCH * 181 * 360;
  size_t n3 = (size_t)NCH * 91 * 180;
  size_t n4 = (size_t)NCH * 46 * 90;
  __hip_bfloat16* bx1 = (__hip_bfloat16*)(base + off); off += n1 * 2;
  __hip_bfloat16* by1 = (__hip_bfloat16*)(base + off); off += n1 * 2;
  off = (off + 255) & ~(size_t)255;
  float* fx2 = (float*)(base + off); off += n2 * 4;
  float* fy2 = (float*)(base + off); off += n2 * 4;
  float* fx3 = (float*)(base + off); off += n3 * 4;
  float* fy3 = (float*)(base + off); off += n3 * 4;
  float* fx4 = (float*)(base + off); off += n4 * 4;
  float* fy4 = (float*)(base + off); off += n4 * 4;
  (void)ws_size; (void)in_sizes; (void)n_in; (void)out_size;

  // scale 0: SSIM + pixel loss + pool -> (bf16) scale-1 inputs
  {
    dim3 g(tx[0], ty[0], NCH);
    k_ssim<float, __hip_bfloat16, true, true, true, 120><<<g, 256, 0, stream>>>(
        x, y, bx1, by1, 721, 1440, 711, 1430, 361, 720, ss_part[0], pix_part, cst);
  }
  // scale 1: SSIM + pool -> (f32) scale-2 inputs
  {
    dim3 g(tx[1], ty[1], NCH);
    k_ssim<__hip_bfloat16, float, false, true, false, 120><<<g, 256, 0, stream>>>(
        bx1, by1, fx2, fy2, 361, 720, 351, 710, 181, 360, ss_part[1], nullptr, cst);
  }
  // scale 2: SSIM + pool
  {
    dim3 g(tx[2], ty[2], NCH);
    k_ssim<float, float, false, true, false, 120><<<g, 256, 0, stream>>>(
        fx2, fy2, fx3, fy3, 181, 360, 171, 350, 91, 180, ss_part[2], nullptr, cst);
  }
  // scale 3: SSIM + pool
  {
    dim3 g(tx[3], ty[3], NCH);
    k_ssim<float, float, false, true, false, 120><<<g, 256, 0, stream>>>(
        fx3, fy3, fx4, fy4, 91, 180, 81, 170, 46, 90, ss_part[3], nullptr, cst);
  }
  // scale 4: SSIM only
  {
    dim3 g(tx[4], ty[4], NCH);
    k_ssim<float, float, false, false, false, 120><<<g, 256, 0, stream>>>(
        fx4, fy4, nullptr, nullptr, 46, 90, 36, 80, 0, 0, ss_part[4], nullptr, cst);
  }

  // merged reductions
  {
    RedArgs ra;
    for (int s = 0; s < 5; ++s) { ra.p[s] = ss_part[s]; ra.tiles[s] = tx[s] * ty[s]; }
    dim3 g(NCH, 5);
    k_reduce_all<<<g, 256, 0, stream>>>(ra, acc);
  }

  k_final<<<1, 256, 0, stream>>>(acc, pix_part, npix_part, out);
}